// Round 5
// baseline (831.037 us; speedup 1.0000x reference)
//
#include <hip/hip_runtime.h>
#include <hip/hip_cooperative_groups.h>
#include <hip/hip_bf16.h>
#include <math.h>

#define NA 2048
#define CP 16

namespace cg = cooperative_groups;

struct FusedParams {
    const float* ql; const float* plm; const float* beta;
    const float* nqw; const float* nqb; const float* npw; const float* npb;
    const float* Wq; const float* bq; const float* Wk; const float* Wv;
    const float* Wpb; const float* Wg; const float* Wo;
    const float* tlw; const float* tlb;
    const float* W1; const float* b1; const float* W2; const float* b2;
    float* out;
    __hip_bfloat16* biasT;
    float* q_ws; float* g_ws; float* kT_ws; float* vT_ws; float* ag_ws;
};

// ===================== FUSED cooperative kernel (512 blocks x 256) =====================
// NO min-occupancy clause: compiler free up to 256 VGPR; 2 blocks/CU co-residency
// guaranteed (LDS 34KB x2 <= 160KB, VGPR <= 256 -> 2 waves/SIMD x 4 = 8 waves/CU).
// Phase bodies are the exact R1-proven kernels, grid-strided.
__global__ __launch_bounds__(256) void fused2_kernel(FusedParams P)
{
    __shared__ __align__(16) char smem[34048];
    const int t = threadIdx.x;
    const int bid = blockIdx.x;
    cg::grid_group grid = cg::this_grid();

    // ---------------- Phase 1a: LN(ql) + q/k/v/g projections (4 rows/block) ----------------
    {
        float* x_lds = (float*)smem;
        float* xn_lds = (float*)(smem + 2048);
        const int row0 = bid * 4;

        for (int idx = t; idx < 512; idx += 256)
            x_lds[idx] = P.ql[(size_t)row0 * 128 + idx];
        __syncthreads();

        if (t < 128) {
            const int r = t >> 5, id = t & 31;
            const float4 x4 = ((const float4*)x_lds)[r * 32 + id];
            float s = x4.x + x4.y + x4.z + x4.w;
            float s2 = x4.x * x4.x + x4.y * x4.y + x4.z * x4.z + x4.w * x4.w;
#pragma unroll
            for (int m = 16; m >= 1; m >>= 1) {
                s += __shfl_xor(s, m);
                s2 += __shfl_xor(s2, m);
            }
            const float mu = s * (1.0f / 128.0f);
            const float inv = rsqrtf(s2 * (1.0f / 128.0f) - mu * mu + 1e-5f);
#pragma unroll
            for (int k = 0; k < 4; ++k) {
                const int c = id * 4 + k;
                xn_lds[r * 128 + c] = (x_lds[r * 128 + c] - mu) * inv * P.nqw[c] + P.nqb[c];
            }
        }
        __syncthreads();

        const float4* xn4 = (const float4*)xn_lds;
#pragma unroll
        for (int cc = 0; cc < 2; ++cc) {
            const int col = cc * 256 + t;
            const int m = col >> 7;        // wave-uniform
            const int cl = col & 127;
            const float* W = (m == 0) ? P.Wq : (m == 1) ? P.Wk : (m == 2) ? P.Wv : P.Wg;
            float acc[4] = {0, 0, 0, 0};
            const float4* wrow = (const float4*)(W + (size_t)cl * 128);
#pragma unroll 8
            for (int k4 = 0; k4 < 32; ++k4) {
                const float4 w4 = wrow[k4];
#pragma unroll
                for (int r = 0; r < 4; ++r) {
                    const float4 a = xn4[r * 32 + k4];
                    acc[r] += a.x * w4.x + a.y * w4.y + a.z * w4.z + a.w * w4.w;
                }
            }
            if (m == 0) {
                const float bb = P.bq[cl];
                const float sc = 0.17677669529663687f; // 1/sqrt(32)
#pragma unroll
                for (int r = 0; r < 4; ++r)
                    P.q_ws[(size_t)(row0 + r) * 128 + cl] = (acc[r] + bb) * sc;
            } else if (m == 1) {
                float4 o; o.x = acc[0]; o.y = acc[1]; o.z = acc[2]; o.w = acc[3];
                *(float4*)(P.kT_ws + (size_t)cl * NA + row0) = o;
            } else if (m == 2) {
                float4 o; o.x = acc[0]; o.y = acc[1]; o.z = acc[2]; o.w = acc[3];
                *(float4*)(P.vT_ws + (size_t)cl * NA + row0) = o;
            } else {
#pragma unroll
                for (int r = 0; r < 4; ++r)
                    P.g_ws[(size_t)(row0 + r) * 128 + cl] = 1.0f / (1.0f + __expf(-acc[r]));
            }
        }
    }

    // ---------------- Phase 1b: bias[h][i][j] = LN(plm)@Wpb.T + beta (16 tiles/block) ----------------
    for (int vb = bid; vb < NA * 4; vb += 512) {
        const int i = vb >> 2;
        const int j0 = (vb & 3) * 512 + t * 2;
        float p[2][4];
#pragma unroll
        for (int e = 0; e < 2; ++e) {
            const size_t base = ((size_t)i * NA + (size_t)(j0 + e)) * CP;
            const float4 x0 = *(const float4*)(P.plm + base);
            const float4 x1 = *(const float4*)(P.plm + base + 4);
            const float4 x2 = *(const float4*)(P.plm + base + 8);
            const float4 x3 = *(const float4*)(P.plm + base + 12);
            float x[16] = {x0.x, x0.y, x0.z, x0.w, x1.x, x1.y, x1.z, x1.w,
                           x2.x, x2.y, x2.z, x2.w, x3.x, x3.y, x3.z, x3.w};
            float s = 0.f, s2 = 0.f;
#pragma unroll
            for (int c = 0; c < 16; ++c) {
                s += x[c];
                s2 = fmaf(x[c], x[c], s2);
            }
            const float mu = s * 0.0625f;
            const float inv = rsqrtf(s2 * 0.0625f - mu * mu + 1e-5f);
            float a0 = 0.f, a1 = 0.f, a2 = 0.f, a3 = 0.f;
#pragma unroll
            for (int c = 0; c < 16; ++c) {
                const float xn = (x[c] - mu) * inv * P.npw[c] + P.npb[c];
                a0 = fmaf(xn, P.Wpb[c], a0);
                a1 = fmaf(xn, P.Wpb[16 + c], a1);
                a2 = fmaf(xn, P.Wpb[32 + c], a2);
                a3 = fmaf(xn, P.Wpb[48 + c], a3);
            }
            p[e][0] = a0; p[e][1] = a1; p[e][2] = a2; p[e][3] = a3;
        }
        const float2 bm = *(const float2*)(P.beta + (size_t)i * NA + j0);
#pragma unroll
        for (int h = 0; h < 4; ++h) {
            const __hip_bfloat162 o =
                __float22bfloat162_rn(make_float2(p[0][h] + bm.x, p[1][h] + bm.y));
            *(__hip_bfloat162*)(P.biasT + (size_t)h * NA * NA + (size_t)i * NA + j0) = o;
        }
    }

    __threadfence();
    grid.sync();

    // ---------------- Phase 2: attention (2 tiles/block) ----------------
    for (int tile = bid; tile < NA / 2; tile += 512) {
        unsigned short (*Lp)[2048] = reinterpret_cast<unsigned short (*)[2048]>(smem);
        float* q_s = (float*)(smem + 32768);
        float* redA = (float*)(smem + 33792);
        float* redB = (float*)(smem + 33920);

        const int h = tile & 3;
        const int i0 = (tile >> 2) * 8;
        const int w = t >> 6, lane = t & 63;
        const int jq = w * 512;

        q_s[t] = P.q_ws[(size_t)(i0 + (t >> 5)) * 128 + h * 32 + (t & 31)];
        __syncthreads();

        float4 La[8], Lb[8];
#pragma unroll
        for (int r = 0; r < 8; ++r) {
            const __hip_bfloat16* base = P.biasT + (size_t)h * NA * NA + (size_t)(i0 + r) * NA;
            const __hip_bfloat162* ba = (const __hip_bfloat162*)(base + jq + lane * 4);
            const float2 f0 = __bfloat1622float2(ba[0]);
            const float2 f1 = __bfloat1622float2(ba[1]);
            La[r] = make_float4(f0.x, f0.y, f1.x, f1.y);
            const __hip_bfloat162* bb = (const __hip_bfloat162*)(base + jq + 256 + lane * 4);
            const float2 g0 = __bfloat1622float2(bb[0]);
            const float2 g1 = __bfloat1622float2(bb[1]);
            Lb[r] = make_float4(g0.x, g0.y, g1.x, g1.y);
        }

        const float* kb = P.kT_ws + (size_t)(h * 32) * NA + jq + lane * 4;
#pragma unroll 4
        for (int c = 0; c < 32; ++c) {
            const float4 ka = *(const float4*)(kb + (size_t)c * NA);
            const float4 kc = *(const float4*)(kb + (size_t)c * NA + 256);
#pragma unroll
            for (int r = 0; r < 8; ++r) {
                const float qv = q_s[r * 32 + c];
                La[r].x += qv * ka.x; La[r].y += qv * ka.y;
                La[r].z += qv * ka.z; La[r].w += qv * ka.w;
                Lb[r].x += qv * kc.x; Lb[r].y += qv * kc.y;
                Lb[r].z += qv * kc.z; Lb[r].w += qv * kc.w;
            }
        }

#pragma unroll
        for (int r = 0; r < 8; ++r) {
            float m = fmaxf(fmaxf(fmaxf(La[r].x, La[r].y), fmaxf(La[r].z, La[r].w)),
                            fmaxf(fmaxf(Lb[r].x, Lb[r].y), fmaxf(Lb[r].z, Lb[r].w)));
#pragma unroll
            for (int mk = 32; mk >= 1; mk >>= 1) m = fmaxf(m, __shfl_xor(m, mk));
            if (lane == 0) redA[w * 8 + r] = m;
        }
        __syncthreads();
#pragma unroll
        for (int r = 0; r < 8; ++r) {
            const float m = fmaxf(fmaxf(redA[r], redA[8 + r]), fmaxf(redA[16 + r], redA[24 + r]));
            La[r].x = __expf(La[r].x - m); La[r].y = __expf(La[r].y - m);
            La[r].z = __expf(La[r].z - m); La[r].w = __expf(La[r].w - m);
            Lb[r].x = __expf(Lb[r].x - m); Lb[r].y = __expf(Lb[r].y - m);
            Lb[r].z = __expf(Lb[r].z - m); Lb[r].w = __expf(Lb[r].w - m);
            float s = La[r].x + La[r].y + La[r].z + La[r].w +
                      Lb[r].x + Lb[r].y + Lb[r].z + Lb[r].w;
#pragma unroll
            for (int mk = 32; mk >= 1; mk >>= 1) s += __shfl_xor(s, mk);
            if (lane == 0) redB[w * 8 + r] = s;
        }
        __syncthreads();
#pragma unroll
        for (int r = 0; r < 8; ++r) {
            const float invl = 1.0f / (redB[r] + redB[8 + r] + redB[16 + r] + redB[24 + r]);
            __hip_bfloat162* d = (__hip_bfloat162*)&Lp[r][jq + lane * 4];
            d[0] = __float22bfloat162_rn(make_float2(La[r].x * invl, La[r].y * invl));
            d[1] = __float22bfloat162_rn(make_float2(La[r].z * invl, La[r].w * invl));
            __hip_bfloat162* d2 = (__hip_bfloat162*)&Lp[r][jq + 256 + lane * 4];
            d2[0] = __float22bfloat162_rn(make_float2(Lb[r].x * invl, Lb[r].y * invl));
            d2[1] = __float22bfloat162_rn(make_float2(Lb[r].z * invl, Lb[r].w * invl));
        }
        __syncthreads();

        float o[8][8];
#pragma unroll
        for (int r = 0; r < 8; ++r)
#pragma unroll
            for (int cc = 0; cc < 8; ++cc) o[r][cc] = 0.0f;

        const float* vb0 = P.vT_ws + (size_t)(h * 32 + w * 8) * NA;
#pragma unroll 2
        for (int jf = 0; jf < 8; ++jf) {
            const int joff = jf * 256 + lane * 4;
            float2 pa[8], pb[8];
#pragma unroll
            for (int r = 0; r < 8; ++r) {
                const uint2 u = *(const uint2*)&Lp[r][joff];
                pa[r] = __bfloat1622float2(*(const __hip_bfloat162*)&u.x);
                pb[r] = __bfloat1622float2(*(const __hip_bfloat162*)&u.y);
            }
#pragma unroll
            for (int cc = 0; cc < 8; ++cc) {
                const float4 v4 = *(const float4*)(vb0 + (size_t)cc * NA + joff);
#pragma unroll
                for (int r = 0; r < 8; ++r) {
                    o[r][cc] += pa[r].x * v4.x + pa[r].y * v4.y +
                                pb[r].x * v4.z + pb[r].y * v4.w;
                }
            }
        }

        __syncthreads();                 // all Lp reads done; reuse its space
        float* op = (float*)smem;        // [w*8+r][cc][8] = 2048 floats
#pragma unroll
        for (int r = 0; r < 8; ++r) {
#pragma unroll
            for (int cc = 0; cc < 8; ++cc) {
                float s = o[r][cc];
                s += __shfl_xor(s, 32);
                s += __shfl_xor(s, 16);
                s += __shfl_xor(s, 8);
                o[r][cc] = s;
            }
        }
        if (lane < 8) {
#pragma unroll
            for (int r = 0; r < 8; ++r)
#pragma unroll
                for (int cc = 0; cc < 8; ++cc)
                    op[((w * 8 + r) * 8 + cc) * 8 + lane] = o[r][cc];
        }
        __syncthreads();

        {
            const float4 a = ((const float4*)op)[t * 2];
            const float4 b = ((const float4*)op)[t * 2 + 1];
            const float s = a.x + a.y + a.z + a.w + b.x + b.y + b.z + b.w;
            const int r = (t >> 3) & 7;
            const int c = (t >> 6) * 8 + (t & 7);
            const float g = P.g_ws[(size_t)(i0 + r) * 128 + h * 32 + c];
            P.ag_ws[(size_t)(i0 + r) * 128 + h * 32 + c] = s * g;
        }
        __syncthreads();                 // smem safe for next tile
    }

    __threadfence();
    grid.sync();

    // ---------------- Phase 3: Wo + residual + LN + MLP + residual (4 rows/block) ----------------
    {
        float* a_lds  = (float*)smem;
        float* ql2_lds = (float*)(smem + 2048);
        float* t_lds  = (float*)(smem + 4096);
        float* h1_lds = (float*)(smem + 6144);
        const int row0 = bid * 4;

        for (int idx = t; idx < 512; idx += 256)
            a_lds[idx] = P.ag_ws[(size_t)row0 * 128 + idx];
        __syncthreads();

        {
            const int col = t >> 1, kh = t & 1;
            float p[4] = {0, 0, 0, 0};
            const float4* wr = (const float4*)(P.Wo + (size_t)col * 128 + kh * 64);
            const float4* a4 = (const float4*)a_lds;
#pragma unroll 8
            for (int k4 = 0; k4 < 16; ++k4) {
                const float4 w4 = wr[k4];
#pragma unroll
                for (int r = 0; r < 4; ++r) {
                    const float4 a = a4[r * 32 + kh * 16 + k4];
                    p[r] += a.x * w4.x + a.y * w4.y + a.z * w4.z + a.w * w4.w;
                }
            }
#pragma unroll
            for (int r = 0; r < 4; ++r) p[r] += __shfl_xor(p[r], 1);
            if (kh == 0) {
#pragma unroll
                for (int r = 0; r < 4; ++r)
                    ql2_lds[r * 128 + col] = P.ql[(size_t)(row0 + r) * 128 + col] + p[r];
            }
        }
        __syncthreads();

        if (t < 128) {
            const int r = t >> 5, id = t & 31;
            const float4 x4 = ((const float4*)ql2_lds)[r * 32 + id];
            float s = x4.x + x4.y + x4.z + x4.w;
            float s2 = x4.x * x4.x + x4.y * x4.y + x4.z * x4.z + x4.w * x4.w;
#pragma unroll
            for (int m = 16; m >= 1; m >>= 1) {
                s += __shfl_xor(s, m);
                s2 += __shfl_xor(s2, m);
            }
            const float mu = s * (1.0f / 128.0f);
            const float inv = rsqrtf(s2 * (1.0f / 128.0f) - mu * mu + 1e-5f);
#pragma unroll
            for (int k = 0; k < 4; ++k) {
                const int c = id * 4 + k;
                t_lds[r * 128 + c] = (ql2_lds[r * 128 + c] - mu) * inv * P.tlw[c] + P.tlb[c];
            }
        }
        __syncthreads();

        const float4* t4 = (const float4*)t_lds;
#pragma unroll
        for (int cc = 0; cc < 2; ++cc) {
            const int col = cc * 256 + t;
            float acc[4] = {0, 0, 0, 0};
            const float4* wr = (const float4*)(P.W1 + (size_t)col * 128);
#pragma unroll 8
            for (int k4 = 0; k4 < 32; ++k4) {
                const float4 w4 = wr[k4];
#pragma unroll
                for (int r = 0; r < 4; ++r) {
                    const float4 a = t4[r * 32 + k4];
                    acc[r] += a.x * w4.x + a.y * w4.y + a.z * w4.z + a.w * w4.w;
                }
            }
            const float bb = P.b1[col];
#pragma unroll
            for (int r = 0; r < 4; ++r)
                h1_lds[r * 512 + col] = fmaxf(acc[r] + bb, 0.0f);
        }
        __syncthreads();

        {
            const int col = t >> 1, kh = t & 1;
            float p[4] = {0, 0, 0, 0};
            const float4* wr = (const float4*)(P.W2 + (size_t)col * 512 + kh * 256);
            const float4* h4 = (const float4*)h1_lds;
#pragma unroll 8
            for (int k4 = 0; k4 < 64; ++k4) {
                const float4 w4 = wr[k4];
#pragma unroll
                for (int r = 0; r < 4; ++r) {
                    const float4 a = h4[r * 128 + kh * 64 + k4];
                    p[r] += a.x * w4.x + a.y * w4.y + a.z * w4.z + a.w * w4.w;
                }
            }
#pragma unroll
            for (int r = 0; r < 4; ++r) p[r] += __shfl_xor(p[r], 1);
            if (kh == 0) {
                const float bb = P.b2[col];
#pragma unroll
                for (int r = 0; r < 4; ++r)
                    P.out[(size_t)(row0 + r) * 128 + col] = ql2_lds[r * 128 + col] + p[r] + bb;
            }
        }
    }
}

// ===================== Fallback: proven 4-kernel pipeline (Round 1, 523 µs) =====================
__global__ __launch_bounds__(256) void bias_kernel(
    const float* __restrict__ plm, const float* __restrict__ beta_mask,
    const float* __restrict__ npw, const float* __restrict__ npb,
    const float* __restrict__ Wpb,
    __hip_bfloat16* __restrict__ biasT)
{
    const int t = threadIdx.x;
    const int i = blockIdx.x >> 2;
    const int j0 = (blockIdx.x & 3) * 512 + t * 2;

    float p[2][4];
#pragma unroll
    for (int e = 0; e < 2; ++e) {
        const size_t base = ((size_t)i * NA + (size_t)(j0 + e)) * CP;
        const float4 x0 = *(const float4*)(plm + base);
        const float4 x1 = *(const float4*)(plm + base + 4);
        const float4 x2 = *(const float4*)(plm + base + 8);
        const float4 x3 = *(const float4*)(plm + base + 12);
        float x[16] = {x0.x, x0.y, x0.z, x0.w, x1.x, x1.y, x1.z, x1.w,
                       x2.x, x2.y, x2.z, x2.w, x3.x, x3.y, x3.z, x3.w};
        float s = 0.f, s2 = 0.f;
#pragma unroll
        for (int c = 0; c < 16; ++c) { s += x[c]; s2 = fmaf(x[c], x[c], s2); }
        const float mu = s * 0.0625f;
        const float inv = rsqrtf(s2 * 0.0625f - mu * mu + 1e-5f);
        float a0 = 0.f, a1 = 0.f, a2 = 0.f, a3 = 0.f;
#pragma unroll
        for (int c = 0; c < 16; ++c) {
            const float xn = (x[c] - mu) * inv * npw[c] + npb[c];
            a0 = fmaf(xn, Wpb[c], a0);
            a1 = fmaf(xn, Wpb[16 + c], a1);
            a2 = fmaf(xn, Wpb[32 + c], a2);
            a3 = fmaf(xn, Wpb[48 + c], a3);
        }
        p[e][0] = a0; p[e][1] = a1; p[e][2] = a2; p[e][3] = a3;
    }
    const float2 bm = *(const float2*)(beta_mask + (size_t)i * NA + j0);
#pragma unroll
    for (int h = 0; h < 4; ++h) {
        const __hip_bfloat162 o =
            __float22bfloat162_rn(make_float2(p[0][h] + bm.x, p[1][h] + bm.y));
        *(__hip_bfloat162*)(biasT + (size_t)h * NA * NA + (size_t)i * NA + j0) = o;
    }
}

__global__ __launch_bounds__(256) void qkvg_kernel(
    const float* __restrict__ ql,
    const float* __restrict__ nqw, const float* __restrict__ nqb,
    const float* __restrict__ Wq, const float* __restrict__ bq,
    const float* __restrict__ Wk, const float* __restrict__ Wv,
    const float* __restrict__ Wg,
    float* __restrict__ q_out, float* __restrict__ kT_out,
    float* __restrict__ vT_out, float* __restrict__ g_out)
{
    __shared__ float x_lds[4 * 128];
    __shared__ float xn_lds[4 * 128];
    const int t = threadIdx.x;
    const int row0 = blockIdx.x * 4;

    for (int idx = t; idx < 512; idx += 256)
        x_lds[idx] = ql[(size_t)row0 * 128 + idx];
    __syncthreads();

    if (t < 128) {
        const int r = t >> 5, id = t & 31;
        const float4 x4 = ((const float4*)x_lds)[r * 32 + id];
        float s = x4.x + x4.y + x4.z + x4.w;
        float s2 = x4.x * x4.x + x4.y * x4.y + x4.z * x4.z + x4.w * x4.w;
#pragma unroll
        for (int m = 16; m >= 1; m >>= 1) { s += __shfl_xor(s, m); s2 += __shfl_xor(s2, m); }
        const float mu = s * (1.0f / 128.0f);
        const float inv = rsqrtf(s2 * (1.0f / 128.0f) - mu * mu + 1e-5f);
#pragma unroll
        for (int k = 0; k < 4; ++k) {
            const int c = id * 4 + k;
            xn_lds[r * 128 + c] = (x_lds[r * 128 + c] - mu) * inv * nqw[c] + nqb[c];
        }
    }
    __syncthreads();

    const float4* xn4 = (const float4*)xn_lds;
#pragma unroll
    for (int cc = 0; cc < 2; ++cc) {
        const int col = cc * 256 + t;
        const int m = col >> 7;
        const int cl = col & 127;
        const float* W = (m == 0) ? Wq : (m == 1) ? Wk : (m == 2) ? Wv : Wg;
        float acc[4] = {0, 0, 0, 0};
        const float4* wrow = (const float4*)(W + (size_t)cl * 128);
#pragma unroll 8
        for (int k4 = 0; k4 < 32; ++k4) {
            const float4 w4 = wrow[k4];
#pragma unroll
            for (int r = 0; r < 4; ++r) {
                const float4 a = xn4[r * 32 + k4];
                acc[r] += a.x * w4.x + a.y * w4.y + a.z * w4.z + a.w * w4.w;
            }
        }
        if (m == 0) {
            const float bb = bq[cl];
            const float sc = 0.17677669529663687f;
#pragma unroll
            for (int r = 0; r < 4; ++r)
                q_out[(size_t)(row0 + r) * 128 + cl] = (acc[r] + bb) * sc;
        } else if (m == 1) {
            float4 o; o.x = acc[0]; o.y = acc[1]; o.z = acc[2]; o.w = acc[3];
            *(float4*)(kT_out + (size_t)cl * NA + row0) = o;
        } else if (m == 2) {
            float4 o; o.x = acc[0]; o.y = acc[1]; o.z = acc[2]; o.w = acc[3];
            *(float4*)(vT_out + (size_t)cl * NA + row0) = o;
        } else {
#pragma unroll
            for (int r = 0; r < 4; ++r)
                g_out[(size_t)(row0 + r) * 128 + cl] = 1.0f / (1.0f + __expf(-acc[r]));
        }
    }
}

__global__ __launch_bounds__(256) void attn_kernel(
    const __hip_bfloat16* __restrict__ biasT,
    const float* __restrict__ q_ws, const float* __restrict__ kT,
    const float* __restrict__ vT, const float* __restrict__ g_ws,
    float* __restrict__ attn_g)
{
    __shared__ unsigned short Lp[8][2048];
    __shared__ float q_s[8 * 32];
    __shared__ float redA[4 * 8];
    __shared__ float redB[4 * 8];

    const int t = threadIdx.x;
    const int h = blockIdx.x & 3;
    const int i0 = (blockIdx.x >> 2) * 8;
    const int w = t >> 6, lane = t & 63;
    const int jq = w * 512;

    q_s[t] = q_ws[(size_t)(i0 + (t >> 5)) * 128 + h * 32 + (t & 31)];
    __syncthreads();

    float4 La[8], Lb[8];
#pragma unroll
    for (int r = 0; r < 8; ++r) {
        const __hip_bfloat16* base = biasT + (size_t)h * NA * NA + (size_t)(i0 + r) * NA;
        const __hip_bfloat162* ba = (const __hip_bfloat162*)(base + jq + lane * 4);
        const float2 f0 = __bfloat1622float2(ba[0]);
        const float2 f1 = __bfloat1622float2(ba[1]);
        La[r] = make_float4(f0.x, f0.y, f1.x, f1.y);
        const __hip_bfloat162* bb = (const __hip_bfloat162*)(base + jq + 256 + lane * 4);
        const float2 g0 = __bfloat1622float2(bb[0]);
        const float2 g1 = __bfloat1622float2(bb[1]);
        Lb[r] = make_float4(g0.x, g0.y, g1.x, g1.y);
    }

    const float* kb = kT + (size_t)(h * 32) * NA + jq + lane * 4;
#pragma unroll 4
    for (int c = 0; c < 32; ++c) {
        const float4 ka = *(const float4*)(kb + (size_t)c * NA);
        const float4 kc = *(const float4*)(kb + (size_t)c * NA + 256);
#pragma unroll
        for (int r = 0; r < 8; ++r) {
            const float qv = q_s[r * 32 + c];
            La[r].x += qv * ka.x; La[r].y += qv * ka.y;
            La[r].z += qv * ka.z; La[r].w += qv * ka.w;
            Lb[r].x += qv * kc.x; Lb[r].y += qv * kc.y;
            Lb[r].z += qv * kc.z; Lb[r].w += qv * kc.w;
        }
    }

#pragma unroll
    for (int r = 0; r < 8; ++r) {
        float m = fmaxf(fmaxf(fmaxf(La[r].x, La[r].y), fmaxf(La[r].z, La[r].w)),
                        fmaxf(fmaxf(Lb[r].x, Lb[r].y), fmaxf(Lb[r].z, Lb[r].w)));
#pragma unroll
        for (int mk = 32; mk >= 1; mk >>= 1) m = fmaxf(m, __shfl_xor(m, mk));
        if (lane == 0) redA[w * 8 + r] = m;
    }
    __syncthreads();
#pragma unroll
    for (int r = 0; r < 8; ++r) {
        const float m = fmaxf(fmaxf(redA[r], redA[8 + r]), fmaxf(redA[16 + r], redA[24 + r]));
        La[r].x = __expf(La[r].x - m); La[r].y = __expf(La[r].y - m);
        La[r].z = __expf(La[r].z - m); La[r].w = __expf(La[r].w - m);
        Lb[r].x = __expf(Lb[r].x - m); Lb[r].y = __expf(Lb[r].y - m);
        Lb[r].z = __expf(Lb[r].z - m); Lb[r].w = __expf(Lb[r].w - m);
        float s = La[r].x + La[r].y + La[r].z + La[r].w +
                  Lb[r].x + Lb[r].y + Lb[r].z + Lb[r].w;
#pragma unroll
        for (int mk = 32; mk >= 1; mk >>= 1) s += __shfl_xor(s, mk);
        if (lane == 0) redB[w * 8 + r] = s;
    }
    __syncthreads();
#pragma unroll
    for (int r = 0; r < 8; ++r) {
        const float invl = 1.0f / (redB[r] + redB[8 + r] + redB[16 + r] + redB[24 + r]);
        __hip_bfloat162* d = (__hip_bfloat162*)&Lp[r][jq + lane * 4];
        d[0] = __float22bfloat162_rn(make_float2(La[r].x * invl, La[r].y * invl));
        d[1] = __float22bfloat162_rn(make_float2(La[r].z * invl, La[r].w * invl));
        __hip_bfloat162* d2 = (__hip_bfloat162*)&Lp[r][jq + 256 + lane * 4];
        d2[0] = __float22bfloat162_rn(make_float2(Lb[r].x * invl, Lb[r].y * invl));
        d2[1] = __float22bfloat162_rn(make_float2(Lb[r].z * invl, Lb[r].w * invl));
    }
    __syncthreads();

    float o[8][8];
#pragma unroll
    for (int r = 0; r < 8; ++r)
#pragma unroll
        for (int cc = 0; cc < 8; ++cc) o[r][cc] = 0.0f;

    const float* vb0 = vT + (size_t)(h * 32 + w * 8) * NA;
#pragma unroll 2
    for (int jf = 0; jf < 8; ++jf) {
        const int joff = jf * 256 + lane * 4;
        float2 pa[8], pb[8];
#pragma unroll
        for (int r = 0; r < 8; ++r) {
            const uint2 u = *(const uint2*)&Lp[r][joff];
            pa[r] = __bfloat1622float2(*(const __hip_bfloat162*)&u.x);
            pb[r] = __bfloat1622float2(*(const __hip_bfloat162*)&u.y);
        }
#pragma unroll
        for (int cc = 0; cc < 8; ++cc) {
            const float4 v4 = *(const float4*)(vb0 + (size_t)cc * NA + joff);
#pragma unroll
            for (int r = 0; r < 8; ++r) {
                o[r][cc] += pa[r].x * v4.x + pa[r].y * v4.y +
                            pb[r].x * v4.z + pb[r].y * v4.w;
            }
        }
    }

    __syncthreads();
    float* op = (float*)&Lp[0][0];
#pragma unroll
    for (int r = 0; r < 8; ++r) {
#pragma unroll
        for (int cc = 0; cc < 8; ++cc) {
            float s = o[r][cc];
            s += __shfl_xor(s, 32);
            s += __shfl_xor(s, 16);
            s += __shfl_xor(s, 8);
            o[r][cc] = s;
        }
    }
    if (lane < 8) {
#pragma unroll
        for (int r = 0; r < 8; ++r)
#pragma unroll
            for (int cc = 0; cc < 8; ++cc)
                op[((w * 8 + r) * 8 + cc) * 8 + lane] = o[r][cc];
    }
    __syncthreads();

    {
        const float4 a = ((const float4*)op)[t * 2];
        const float4 b = ((const float4*)op)[t * 2 + 1];
        const float s = a.x + a.y + a.z + a.w + b.x + b.y + b.z + b.w;
        const int r = (t >> 3) & 7;
        const int c = (t >> 6) * 8 + (t & 7);
        const float g = g_ws[(size_t)(i0 + r) * 128 + h * 32 + c];
        attn_g[(size_t)(i0 + r) * 128 + h * 32 + c] = s * g;
    }
}

__global__ __launch_bounds__(256) void out_mlp_kernel(
    const float* __restrict__ ql,
    const float* __restrict__ attn_g,
    const float* __restrict__ Wo,
    const float* __restrict__ tlw, const float* __restrict__ tlb,
    const float* __restrict__ W1, const float* __restrict__ b1,
    const float* __restrict__ W2, const float* __restrict__ b2,
    float* __restrict__ out)
{
    __shared__ float a_lds[4 * 128];
    __shared__ float ql2_lds[4 * 128];
    __shared__ float t_lds[4 * 128];
    __shared__ float h1_lds[4 * 512];
    const int t = threadIdx.x;
    const int row0 = blockIdx.x * 4;

    for (int idx = t; idx < 512; idx += 256)
        a_lds[idx] = attn_g[(size_t)row0 * 128 + idx];
    __syncthreads();

    {
        const int col = t >> 1, kh = t & 1;
        float p[4] = {0, 0, 0, 0};
        const float4* wr = (const float4*)(Wo + (size_t)col * 128 + kh * 64);
        const float4* a4 = (const float4*)a_lds;
#pragma unroll 8
        for (int k4 = 0; k4 < 16; ++k4) {
            const float4 w4 = wr[k4];
#pragma unroll
            for (int r = 0; r < 4; ++r) {
                const float4 a = a4[r * 32 + kh * 16 + k4];
                p[r] += a.x * w4.x + a.y * w4.y + a.z * w4.z + a.w * w4.w;
            }
        }
#pragma unroll
        for (int r = 0; r < 4; ++r) p[r] += __shfl_xor(p[r], 1);
        if (kh == 0) {
#pragma unroll
            for (int r = 0; r < 4; ++r)
                ql2_lds[r * 128 + col] = ql[(size_t)(row0 + r) * 128 + col] + p[r];
        }
    }
    __syncthreads();

    if (t < 128) {
        const int r = t >> 5, id = t & 31;
        const float4 x4 = ((const float4*)ql2_lds)[r * 32 + id];
        float s = x4.x + x4.y + x4.z + x4.w;
        float s2 = x4.x * x4.x + x4.y * x4.y + x4.z * x4.z + x4.w * x4.w;
#pragma unroll
        for (int m = 16; m >= 1; m >>= 1) { s += __shfl_xor(s, m); s2 += __shfl_xor(s2, m); }
        const float mu = s * (1.0f / 128.0f);
        const float inv = rsqrtf(s2 * (1.0f / 128.0f) - mu * mu + 1e-5f);
#pragma unroll
        for (int k = 0; k < 4; ++k) {
            const int c = id * 4 + k;
            t_lds[r * 128 + c] = (ql2_lds[r * 128 + c] - mu) * inv * tlw[c] + tlb[c];
        }
    }
    __syncthreads();

    const float4* t4 = (const float4*)t_lds;
#pragma unroll
    for (int cc = 0; cc < 2; ++cc) {
        const int col = cc * 256 + t;
        float acc[4] = {0, 0, 0, 0};
        const float4* wr = (const float4*)(W1 + (size_t)col * 128);
#pragma unroll 8
        for (int k4 = 0; k4 < 32; ++k4) {
            const float4 w4 = wr[k4];
#pragma unroll
            for (int r = 0; r < 4; ++r) {
                const float4 a = t4[r * 32 + k4];
                acc[r] += a.x * w4.x + a.y * w4.y + a.z * w4.z + a.w * w4.w;
            }
        }
        const float bb = b1[col];
#pragma unroll
        for (int r = 0; r < 4; ++r)
            h1_lds[r * 512 + col] = fmaxf(acc[r] + bb, 0.0f);
    }
    __syncthreads();

    {
        const int col = t >> 1, kh = t & 1;
        float p[4] = {0, 0, 0, 0};
        const float4* wr = (const float4*)(W2 + (size_t)col * 512 + kh * 256);
        const float4* h4 = (const float4*)h1_lds;
#pragma unroll 8
        for (int k4 = 0; k4 < 64; ++k4) {
            const float4 w4 = wr[k4];
#pragma unroll
            for (int r = 0; r < 4; ++r) {
                const float4 a = h4[r * 128 + kh * 64 + k4];
                p[r] += a.x * w4.x + a.y * w4.y + a.z * w4.z + a.w * w4.w;
            }
        }
#pragma unroll
        for (int r = 0; r < 4; ++r) p[r] += __shfl_xor(p[r], 1);
        if (kh == 0) {
            const float bb = b2[col];
#pragma unroll
            for (int r = 0; r < 4; ++r)
                out[(size_t)(row0 + r) * 128 + col] = ql2_lds[r * 128 + col] + p[r] + bb;
        }
    }
}

extern "C" void kernel_launch(void* const* d_in, const int* in_sizes, int n_in,
                              void* d_out, int out_size, void* d_ws, size_t ws_size,
                              hipStream_t stream) {
    const float* ql   = (const float*)d_in[0];
    // d_in[1] = cl : unused by the reference
    const float* plm  = (const float*)d_in[2];
    const float* beta = (const float*)d_in[3];
    const float* nqw  = (const float*)d_in[4];
    const float* nqb  = (const float*)d_in[5];
    const float* npw  = (const float*)d_in[6];
    const float* npb  = (const float*)d_in[7];
    const float* Wq   = (const float*)d_in[8];
    const float* bq   = (const float*)d_in[9];
    const float* Wk   = (const float*)d_in[10];
    const float* Wv   = (const float*)d_in[11];
    const float* Wpb  = (const float*)d_in[12];
    const float* Wg   = (const float*)d_in[13];
    const float* Wo   = (const float*)d_in[14];
    const float* tlw  = (const float*)d_in[15];
    const float* tlb  = (const float*)d_in[16];
    const float* W1   = (const float*)d_in[17];
    const float* b1   = (const float*)d_in[18];
    const float* W2   = (const float*)d_in[19];
    const float* b2   = (const float*)d_in[20];
    float* out = (float*)d_out;

    // workspace layout (bytes): bias bf16 33.5 MB, then 5 fp32 1-MB buffers
    char* ws = (char*)d_ws;
    __hip_bfloat16* biasT = (__hip_bfloat16*)ws;                  // 4*2048*2048*2
    float* q_ws  = (float*)(ws + 33554432);
    float* g_ws  = (float*)(ws + 33554432 + 1 * 1048576);
    float* kT_ws = (float*)(ws + 33554432 + 2 * 1048576);
    float* vT_ws = (float*)(ws + 33554432 + 3 * 1048576);
    float* ag_ws = (float*)(ws + 33554432 + 4 * 1048576);

    FusedParams P;
    P.ql = ql; P.plm = plm; P.beta = beta;
    P.nqw = nqw; P.nqb = nqb; P.npw = npw; P.npb = npb;
    P.Wq = Wq; P.bq = bq; P.Wk = Wk; P.Wv = Wv; P.Wpb = Wpb;
    P.Wg = Wg; P.Wo = Wo; P.tlw = tlw; P.tlb = tlb;
    P.W1 = W1; P.b1 = b1; P.W2 = W2; P.b2 = b2;
    P.out = out; P.biasT = biasT;
    P.q_ws = q_ws; P.g_ws = g_ws; P.kT_ws = kT_ws; P.vT_ws = vT_ws; P.ag_ws = ag_ws;

    void* args[] = {&P};
    hipError_t err = hipLaunchCooperativeKernel(
        reinterpret_cast<const void*>(&fused2_kernel),
        dim3(512), dim3(256), args, 0, stream);

    if (err != hipSuccess) {
        (void)hipGetLastError();  // clear sticky error, fall back to proven 4-kernel path
        bias_kernel<<<NA * 4, 256, 0, stream>>>(plm, beta, npw, npb, Wpb, biasT);
        qkvg_kernel<<<NA / 4, 256, 0, stream>>>(ql, nqw, nqb, Wq, bq, Wk, Wv, Wg,
                                                q_ws, kT_ws, vT_ws, g_ws);
        attn_kernel<<<NA / 2, 256, 0, stream>>>(biasT, q_ws, kT_ws, vT_ws, g_ws, ag_ws);
        out_mlp_kernel<<<NA / 4, 256, 0, stream>>>(ql, ag_ws, Wo, tlw, tlb,
                                                   W1, b1, W2, b2, out);
    }
}

// Round 8
// 519.882 us; speedup vs baseline: 1.5985x; 1.5985x over previous
//
#include <hip/hip_runtime.h>
#include <hip/hip_bf16.h>
#include <math.h>

#define NA 2048
#define CP 16

// ===== Kernel A: merged producer kernel =====
// blocks [0, 512)    : LN(ql) + q/k/v/gate projections (4 rows/block)  [R1-exact]
// blocks [512, 8704) : bias[h][i][j] = LN(plm)@Wpb.T + beta (bf16)     [R1-exact]
__global__ __launch_bounds__(256) void prod_kernel(
    const float* __restrict__ plm, const float* __restrict__ beta_mask,
    const float* __restrict__ npw, const float* __restrict__ npb,
    const float* __restrict__ Wpb,
    __hip_bfloat16* __restrict__ biasT,
    const float* __restrict__ ql,
    const float* __restrict__ nqw, const float* __restrict__ nqb,
    const float* __restrict__ Wq, const float* __restrict__ bq,
    const float* __restrict__ Wk, const float* __restrict__ Wv,
    const float* __restrict__ Wg,
    float* __restrict__ q_out, float* __restrict__ kT_out,
    float* __restrict__ vT_out, float* __restrict__ g_out)
{
    __shared__ float x_lds[4 * 128];
    __shared__ float xn_lds[4 * 128];
    const int t = threadIdx.x;

    if (blockIdx.x < 512) {
        // ---------------- qkvg path (R1-exact) ----------------
        const int row0 = blockIdx.x * 4;

        for (int idx = t; idx < 512; idx += 256)
            x_lds[idx] = ql[(size_t)row0 * 128 + idx];
        __syncthreads();

        if (t < 128) {
            const int r = t >> 5, id = t & 31;
            const float4 x4 = ((const float4*)x_lds)[r * 32 + id];
            float s = x4.x + x4.y + x4.z + x4.w;
            float s2 = x4.x * x4.x + x4.y * x4.y + x4.z * x4.z + x4.w * x4.w;
#pragma unroll
            for (int m = 16; m >= 1; m >>= 1) {
                s += __shfl_xor(s, m);
                s2 += __shfl_xor(s2, m);
            }
            const float mu = s * (1.0f / 128.0f);
            const float inv = rsqrtf(s2 * (1.0f / 128.0f) - mu * mu + 1e-5f);
#pragma unroll
            for (int k = 0; k < 4; ++k) {
                const int c = id * 4 + k;
                xn_lds[r * 128 + c] = (x_lds[r * 128 + c] - mu) * inv * nqw[c] + nqb[c];
            }
        }
        __syncthreads();

        const float4* xn4 = (const float4*)xn_lds;
#pragma unroll
        for (int cc = 0; cc < 2; ++cc) {
            const int col = cc * 256 + t;
            const int m = col >> 7;        // wave-uniform
            const int cl = col & 127;
            const float* W = (m == 0) ? Wq : (m == 1) ? Wk : (m == 2) ? Wv : Wg;
            float acc[4] = {0, 0, 0, 0};
            const float4* wrow = (const float4*)(W + (size_t)cl * 128);
#pragma unroll 8
            for (int k4 = 0; k4 < 32; ++k4) {
                const float4 w4 = wrow[k4];
#pragma unroll
                for (int r = 0; r < 4; ++r) {
                    const float4 a = xn4[r * 32 + k4];
                    acc[r] += a.x * w4.x + a.y * w4.y + a.z * w4.z + a.w * w4.w;
                }
            }
            if (m == 0) {
                const float bb = bq[cl];
                const float sc = 0.17677669529663687f; // 1/sqrt(32)
#pragma unroll
                for (int r = 0; r < 4; ++r)
                    q_out[(size_t)(row0 + r) * 128 + cl] = (acc[r] + bb) * sc;
            } else if (m == 1) {
                float4 o; o.x = acc[0]; o.y = acc[1]; o.z = acc[2]; o.w = acc[3];
                *(float4*)(kT_out + (size_t)cl * NA + row0) = o;
            } else if (m == 2) {
                float4 o; o.x = acc[0]; o.y = acc[1]; o.z = acc[2]; o.w = acc[3];
                *(float4*)(vT_out + (size_t)cl * NA + row0) = o;
            } else {
#pragma unroll
                for (int r = 0; r < 4; ++r)
                    g_out[(size_t)(row0 + r) * 128 + cl] = 1.0f / (1.0f + __expf(-acc[r]));
            }
        }
        return;
    }

    // ---------------- bias path (R1-exact, cacheable loads) ----------------
    const int vb = blockIdx.x - 512;
    const int i = vb >> 2;
    const int j0 = (vb & 3) * 512 + t * 2;

    float p[2][4];
#pragma unroll
    for (int e = 0; e < 2; ++e) {
        const size_t base = ((size_t)i * NA + (size_t)(j0 + e)) * CP;
        const float4 x0 = *(const float4*)(plm + base);
        const float4 x1 = *(const float4*)(plm + base + 4);
        const float4 x2 = *(const float4*)(plm + base + 8);
        const float4 x3 = *(const float4*)(plm + base + 12);
        float x[16] = {x0.x, x0.y, x0.z, x0.w, x1.x, x1.y, x1.z, x1.w,
                       x2.x, x2.y, x2.z, x2.w, x3.x, x3.y, x3.z, x3.w};
        float s = 0.f, s2 = 0.f;
#pragma unroll
        for (int c = 0; c < 16; ++c) {
            s += x[c];
            s2 = fmaf(x[c], x[c], s2);
        }
        const float mu = s * 0.0625f;
        const float inv = rsqrtf(s2 * 0.0625f - mu * mu + 1e-5f);
        float a0 = 0.f, a1 = 0.f, a2 = 0.f, a3 = 0.f;
#pragma unroll
        for (int c = 0; c < 16; ++c) {
            const float xn = (x[c] - mu) * inv * npw[c] + npb[c];
            a0 = fmaf(xn, Wpb[c], a0);
            a1 = fmaf(xn, Wpb[16 + c], a1);
            a2 = fmaf(xn, Wpb[32 + c], a2);
            a3 = fmaf(xn, Wpb[48 + c], a3);
        }
        p[e][0] = a0; p[e][1] = a1; p[e][2] = a2; p[e][3] = a3;
    }
    const float2 bm = *(const float2*)(beta_mask + (size_t)i * NA + j0);
#pragma unroll
    for (int h = 0; h < 4; ++h) {
        const __hip_bfloat162 o =
            __float22bfloat162_rn(make_float2(p[0][h] + bm.x, p[1][h] + bm.y));
        *(__hip_bfloat162*)(biasT + (size_t)h * NA * NA + (size_t)i * NA + j0) = o;
    }
}

// ===== Kernel B: attention (R1-exact). Block = (head, 8 rows). =====
__global__ __launch_bounds__(256) void attn_kernel(
    const __hip_bfloat16* __restrict__ biasT,
    const float* __restrict__ q_ws, const float* __restrict__ kT,
    const float* __restrict__ vT, const float* __restrict__ g_ws,
    float* __restrict__ attn_g)
{
    __shared__ unsigned short Lp[8][2048];   // p (normalized) bf16: 32 KB
    __shared__ float q_s[8 * 32];
    __shared__ float redA[4 * 8];
    __shared__ float redB[4 * 8];

    const int t = threadIdx.x;
    const int h = blockIdx.x & 3;
    const int i0 = (blockIdx.x >> 2) * 8;
    const int w = t >> 6, lane = t & 63;
    const int jq = w * 512;

    q_s[t] = q_ws[(size_t)(i0 + (t >> 5)) * 128 + h * 32 + (t & 31)];
    __syncthreads();

    // init logits from bias(+beta)
    float4 La[8], Lb[8];
#pragma unroll
    for (int r = 0; r < 8; ++r) {
        const __hip_bfloat16* base = biasT + (size_t)h * NA * NA + (size_t)(i0 + r) * NA;
        const __hip_bfloat162* ba = (const __hip_bfloat162*)(base + jq + lane * 4);
        const float2 f0 = __bfloat1622float2(ba[0]);
        const float2 f1 = __bfloat1622float2(ba[1]);
        La[r] = make_float4(f0.x, f0.y, f1.x, f1.y);
        const __hip_bfloat162* bb = (const __hip_bfloat162*)(base + jq + 256 + lane * 4);
        const float2 g0 = __bfloat1622float2(bb[0]);
        const float2 g1 = __bfloat1622float2(bb[1]);
        Lb[r] = make_float4(g0.x, g0.y, g1.x, g1.y);
    }

    // QK: logits += q . k  (kT coalesced over j; q broadcast from LDS)
    const float* kb = kT + (size_t)(h * 32) * NA + jq + lane * 4;
#pragma unroll 4
    for (int c = 0; c < 32; ++c) {
        const float4 ka = *(const float4*)(kb + (size_t)c * NA);
        const float4 kc = *(const float4*)(kb + (size_t)c * NA + 256);
#pragma unroll
        for (int r = 0; r < 8; ++r) {
            const float qv = q_s[r * 32 + c];
            La[r].x += qv * ka.x; La[r].y += qv * ka.y;
            La[r].z += qv * ka.z; La[r].w += qv * ka.w;
            Lb[r].x += qv * kc.x; Lb[r].y += qv * kc.y;
            Lb[r].z += qv * kc.z; Lb[r].w += qv * kc.w;
        }
    }

    // softmax: wave-partial max -> combine -> exp -> wave-partial sum -> combine
#pragma unroll
    for (int r = 0; r < 8; ++r) {
        float m = fmaxf(fmaxf(fmaxf(La[r].x, La[r].y), fmaxf(La[r].z, La[r].w)),
                        fmaxf(fmaxf(Lb[r].x, Lb[r].y), fmaxf(Lb[r].z, Lb[r].w)));
#pragma unroll
        for (int mk = 32; mk >= 1; mk >>= 1) m = fmaxf(m, __shfl_xor(m, mk));
        if (lane == 0) redA[w * 8 + r] = m;
    }
    __syncthreads();
#pragma unroll
    for (int r = 0; r < 8; ++r) {
        const float m = fmaxf(fmaxf(redA[r], redA[8 + r]), fmaxf(redA[16 + r], redA[24 + r]));
        La[r].x = __expf(La[r].x - m); La[r].y = __expf(La[r].y - m);
        La[r].z = __expf(La[r].z - m); La[r].w = __expf(La[r].w - m);
        Lb[r].x = __expf(Lb[r].x - m); Lb[r].y = __expf(Lb[r].y - m);
        Lb[r].z = __expf(Lb[r].z - m); Lb[r].w = __expf(Lb[r].w - m);
        float s = La[r].x + La[r].y + La[r].z + La[r].w +
                  Lb[r].x + Lb[r].y + Lb[r].z + Lb[r].w;
#pragma unroll
        for (int mk = 32; mk >= 1; mk >>= 1) s += __shfl_xor(s, mk);
        if (lane == 0) redB[w * 8 + r] = s;
    }
    __syncthreads();
#pragma unroll
    for (int r = 0; r < 8; ++r) {
        const float invl = 1.0f / (redB[r] + redB[8 + r] + redB[16 + r] + redB[24 + r]);
        __hip_bfloat162* d = (__hip_bfloat162*)&Lp[r][jq + lane * 4];
        d[0] = __float22bfloat162_rn(make_float2(La[r].x * invl, La[r].y * invl));
        d[1] = __float22bfloat162_rn(make_float2(La[r].z * invl, La[r].w * invl));
        __hip_bfloat162* d2 = (__hip_bfloat162*)&Lp[r][jq + 256 + lane * 4];
        d2[0] = __float22bfloat162_rn(make_float2(Lb[r].x * invl, Lb[r].y * invl));
        d2[1] = __float22bfloat162_rn(make_float2(Lb[r].z * invl, Lb[r].w * invl));
    }
    __syncthreads();

    // PV: wave w owns channels c = w*8 .. w*8+7 over ALL j.
    float o[8][8];   // [r][cc]
#pragma unroll
    for (int r = 0; r < 8; ++r)
#pragma unroll
        for (int cc = 0; cc < 8; ++cc) o[r][cc] = 0.0f;

    const float* vb0 = vT + (size_t)(h * 32 + w * 8) * NA;
#pragma unroll 2
    for (int jf = 0; jf < 8; ++jf) {
        const int joff = jf * 256 + lane * 4;
        float2 pa[8], pb[8];
#pragma unroll
        for (int r = 0; r < 8; ++r) {
            const uint2 u = *(const uint2*)&Lp[r][joff];
            pa[r] = __bfloat1622float2(*(const __hip_bfloat162*)&u.x);
            pb[r] = __bfloat1622float2(*(const __hip_bfloat162*)&u.y);
        }
#pragma unroll
        for (int cc = 0; cc < 8; ++cc) {
            const float4 v4 = *(const float4*)(vb0 + (size_t)cc * NA + joff);
#pragma unroll
            for (int r = 0; r < 8; ++r) {
                o[r][cc] += pa[r].x * v4.x + pa[r].y * v4.y +
                            pb[r].x * v4.z + pb[r].y * v4.w;
            }
        }
    }

    // reduce across lanes: 3-stage xor -> 8 partials per (r,cc), stash in LDS
    __syncthreads();                 // all Lp reads done; reuse its space
    float* op = (float*)&Lp[0][0];   // [w*8+r][cc][8] = 2048 floats
#pragma unroll
    for (int r = 0; r < 8; ++r) {
#pragma unroll
        for (int cc = 0; cc < 8; ++cc) {
            float s = o[r][cc];
            s += __shfl_xor(s, 32);
            s += __shfl_xor(s, 16);
            s += __shfl_xor(s, 8);
            o[r][cc] = s;
        }
    }
    if (lane < 8) {
#pragma unroll
        for (int r = 0; r < 8; ++r)
#pragma unroll
            for (int cc = 0; cc < 8; ++cc)
                op[((w * 8 + r) * 8 + cc) * 8 + lane] = o[r][cc];
    }
    __syncthreads();

    {
        const float4 a = ((const float4*)op)[t * 2];
        const float4 b = ((const float4*)op)[t * 2 + 1];
        const float s = a.x + a.y + a.z + a.w + b.x + b.y + b.z + b.w;
        const int r = (t >> 3) & 7;
        const int c = (t >> 6) * 8 + (t & 7);
        const float g = g_ws[(size_t)(i0 + r) * 128 + h * 32 + c];
        attn_g[(size_t)(i0 + r) * 128 + h * 32 + c] = s * g;
    }
}

// ===== Kernel 3: Wo proj + residual + LN + MLP + residual (R1-exact) =====
__global__ __launch_bounds__(256) void out_mlp_kernel(
    const float* __restrict__ ql,
    const float* __restrict__ attn_g,
    const float* __restrict__ Wo,
    const float* __restrict__ tlw, const float* __restrict__ tlb,
    const float* __restrict__ W1, const float* __restrict__ b1,
    const float* __restrict__ W2, const float* __restrict__ b2,
    float* __restrict__ out)
{
    __shared__ float a_lds[4 * 128];
    __shared__ float ql2_lds[4 * 128];
    __shared__ float t_lds[4 * 128];
    __shared__ float h1_lds[4 * 512];
    const int t = threadIdx.x;
    const int row0 = blockIdx.x * 4;

    for (int idx = t; idx < 512; idx += 256)
        a_lds[idx] = attn_g[(size_t)row0 * 128 + idx];
    __syncthreads();

    // Stage 1: ql2 = ql + a @ Wo.T ; col = t/2, k-half = t&1
    {
        const int col = t >> 1, kh = t & 1;
        float p[4] = {0, 0, 0, 0};
        const float4* wr = (const float4*)(Wo + (size_t)col * 128 + kh * 64);
        const float4* a4 = (const float4*)a_lds;
#pragma unroll 8
        for (int k4 = 0; k4 < 16; ++k4) {
            const float4 w4 = wr[k4];
#pragma unroll
            for (int r = 0; r < 4; ++r) {
                const float4 a = a4[r * 32 + kh * 16 + k4];
                p[r] += a.x * w4.x + a.y * w4.y + a.z * w4.z + a.w * w4.w;
            }
        }
#pragma unroll
        for (int r = 0; r < 4; ++r) p[r] += __shfl_xor(p[r], 1);
        if (kh == 0) {
#pragma unroll
            for (int r = 0; r < 4; ++r)
                ql2_lds[r * 128 + col] = ql[(size_t)(row0 + r) * 128 + col] + p[r];
        }
    }
    __syncthreads();

    // LayerNorm(ql2) -> t_lds
    if (t < 128) {
        const int r = t >> 5, id = t & 31;
        const float4 x4 = ((const float4*)ql2_lds)[r * 32 + id];
        float s = x4.x + x4.y + x4.z + x4.w;
        float s2 = x4.x * x4.x + x4.y * x4.y + x4.z * x4.z + x4.w * x4.w;
#pragma unroll
        for (int m = 16; m >= 1; m >>= 1) {
            s += __shfl_xor(s, m);
            s2 += __shfl_xor(s2, m);
        }
        const float mu = s * (1.0f / 128.0f);
        const float inv = rsqrtf(s2 * (1.0f / 128.0f) - mu * mu + 1e-5f);
#pragma unroll
        for (int k = 0; k < 4; ++k) {
            const int c = id * 4 + k;
            t_lds[r * 128 + c] = (ql2_lds[r * 128 + c] - mu) * inv * tlw[c] + tlb[c];
        }
    }
    __syncthreads();

    // Stage 2: h1 = relu(t @ W1.T + b1), 2 cols/thread, full K
    const float4* t4 = (const float4*)t_lds;
#pragma unroll
    for (int cc = 0; cc < 2; ++cc) {
        const int col = cc * 256 + t;
        float acc[4] = {0, 0, 0, 0};
        const float4* wr = (const float4*)(W1 + (size_t)col * 128);
#pragma unroll 8
        for (int k4 = 0; k4 < 32; ++k4) {
            const float4 w4 = wr[k4];
#pragma unroll
            for (int r = 0; r < 4; ++r) {
                const float4 a = t4[r * 32 + k4];
                acc[r] += a.x * w4.x + a.y * w4.y + a.z * w4.z + a.w * w4.w;
            }
        }
        const float bb = b1[col];
#pragma unroll
        for (int r = 0; r < 4; ++r)
            h1_lds[r * 512 + col] = fmaxf(acc[r] + bb, 0.0f);
    }
    __syncthreads();

    // Stage 3: out = ql2 + h1 @ W2.T + b2 ; col = t/2, k-half = t&1 (K=512)
    {
        const int col = t >> 1, kh = t & 1;
        float p[4] = {0, 0, 0, 0};
        const float4* wr = (const float4*)(W2 + (size_t)col * 512 + kh * 256);
        const float4* h4 = (const float4*)h1_lds;
#pragma unroll 8
        for (int k4 = 0; k4 < 64; ++k4) {
            const float4 w4 = wr[k4];
#pragma unroll
            for (int r = 0; r < 4; ++r) {
                const float4 a = h4[r * 128 + kh * 64 + k4];
                p[r] += a.x * w4.x + a.y * w4.y + a.z * w4.z + a.w * w4.w;
            }
        }
#pragma unroll
        for (int r = 0; r < 4; ++r) p[r] += __shfl_xor(p[r], 1);
        if (kh == 0) {
            const float bb = b2[col];
#pragma unroll
            for (int r = 0; r < 4; ++r)
                out[(size_t)(row0 + r) * 128 + col] = ql2_lds[r * 128 + col] + p[r] + bb;
        }
    }
}

extern "C" void kernel_launch(void* const* d_in, const int* in_sizes, int n_in,
                              void* d_out, int out_size, void* d_ws, size_t ws_size,
                              hipStream_t stream) {
    const float* ql   = (const float*)d_in[0];
    // d_in[1] = cl : unused by the reference
    const float* plm  = (const float*)d_in[2];
    const float* beta = (const float*)d_in[3];
    const float* nqw  = (const float*)d_in[4];
    const float* nqb  = (const float*)d_in[5];
    const float* npw  = (const float*)d_in[6];
    const float* npb  = (const float*)d_in[7];
    const float* Wq   = (const float*)d_in[8];
    const float* bq   = (const float*)d_in[9];
    const float* Wk   = (const float*)d_in[10];
    const float* Wv   = (const float*)d_in[11];
    const float* Wpb  = (const float*)d_in[12];
    const float* Wg   = (const float*)d_in[13];
    const float* Wo   = (const float*)d_in[14];
    const float* tlw  = (const float*)d_in[15];
    const float* tlb  = (const float*)d_in[16];
    const float* W1   = (const float*)d_in[17];
    const float* b1   = (const float*)d_in[18];
    const float* W2   = (const float*)d_in[19];
    const float* b2   = (const float*)d_in[20];
    float* out = (float*)d_out;

    // workspace layout (bytes): bias bf16 33.5 MB, then 5 fp32 1-MB buffers
    char* ws = (char*)d_ws;
    __hip_bfloat16* biasT = (__hip_bfloat16*)ws;                  // 4*2048*2048*2
    float* q_ws  = (float*)(ws + 33554432);
    float* g_ws  = (float*)(ws + 33554432 + 1 * 1048576);
    float* kT_ws = (float*)(ws + 33554432 + 2 * 1048576);
    float* vT_ws = (float*)(ws + 33554432 + 3 * 1048576);
    float* ag_ws = (float*)(ws + 33554432 + 4 * 1048576);

    prod_kernel<<<512 + NA * 4, 256, 0, stream>>>(
        plm, beta, npw, npb, Wpb, biasT,
        ql, nqw, nqb, Wq, bq, Wk, Wv, Wg,
        q_ws, kT_ws, vT_ws, g_ws);
    attn_kernel<<<NA / 2, 256, 0, stream>>>(biasT, q_ws, kT_ws, vT_ws, g_ws, ag_ws);
    out_mlp_kernel<<<NA / 4, 256, 0, stream>>>(ql, ag_ws, Wo, tlw, tlb,
                                               W1, b1, W2, b2, out);
}